// Round 1
// baseline (10570.716 us; speedup 1.0000x reference)
//
#include <hip/hip_runtime.h>
#include <hip/hip_bf16.h>

#define N_NODES 200000
#define N_EDGES 12800000
#define DIM 128

typedef float f32x2 __attribute__((ext_vector_type(2)));
typedef float f32x4 __attribute__((ext_vector_type(4)));
typedef __bf16 bf16x8 __attribute__((ext_vector_type(8)));

// ---------------------------------------------------------------------------
// Phase 1: COO SpMM scatter.  side[r,:] += val * ego[c,:]
// One wave processes 64 edges per outer iteration: each lane loads one edge's
// metadata (coalesced), then we iterate the 64 edges broadcasting metadata via
// v_readlane (uniform j -> SGPR), gather 8 B/lane of ego[c] (512 B coalesced),
// and do 2 HW f32 atomics per lane into side[r].
// ---------------------------------------------------------------------------
__global__ __launch_bounds__(256) void scatter_kernel(
    const int* __restrict__ erow, const int* __restrict__ ecol,
    const float* __restrict__ eval, const float* __restrict__ ego,
    float* __restrict__ side)
{
    const int lane   = threadIdx.x & 63;
    const int wave   = blockIdx.x * (blockDim.x >> 6) + (threadIdx.x >> 6);
    const int nwaves = gridDim.x * (blockDim.x >> 6);
    const int ngroups = N_EDGES / 64;   // 200000

    for (int g = wave; g < ngroups; g += nwaves) {
        const int e = g * 64 + lane;
        const int r = erow[e];
        const int c = ecol[e];
        const float v = eval[e];
        #pragma unroll 4
        for (int j = 0; j < 64; ++j) {
            const int rj = __builtin_amdgcn_readlane(r, j);
            const int cj = __builtin_amdgcn_readlane(c, j);
            const float vj = __int_as_float(__builtin_amdgcn_readlane(__float_as_int(v), j));
            const f32x2 gv = ((const f32x2*)(ego + (size_t)cj * DIM))[lane];
            float* dst = side + (size_t)rj * DIM + lane * 2;
            unsafeAtomicAdd(dst,     vj * gv.x);
            unsafeAtomicAdd(dst + 1, vj * gv.y);
        }
    }
}

// ---------------------------------------------------------------------------
// Phase 2: out = lrelu((ego+side)@W1 + b1) + lrelu((ego*side)@W2 + b2)
// bf16 MFMA 16x16x32.  W1^T, W2^T staged in LDS as bf16 with a 16B-granule
// XOR swizzle (g ^= c&7) so B-fragment ds_read_b128 (16 lanes at 256 B row
// stride) is bank-conflict-free.  Each wave owns a 16-node tile, computes all
// 128 output columns (8 column tiles x 4 k-steps = 64 MFMAs per tile).
// In-place: side_in == out is safe (stores data-depend on all tile loads).
// ---------------------------------------------------------------------------
__device__ __forceinline__ int swz(int c, int k) {
    // index into a [128][128] bf16 row-major LDS tile, 16B-granule swizzled
    return c * DIM + ((((k >> 3) ^ (c & 7)) << 3) | (k & 7));
}

__global__ __launch_bounds__(256) void dense_kernel(
    const float* __restrict__ ego, const float* side_in,
    const float* __restrict__ W1, const float* __restrict__ b1,
    const float* __restrict__ W2, const float* __restrict__ b2,
    float* out)
{
    __shared__ __bf16 w1t[DIM * DIM];   // w1t[c][k] = W1[k][c]  (swizzled)
    __shared__ __bf16 w2t[DIM * DIM];

    for (int idx = threadIdx.x; idx < DIM * DIM; idx += blockDim.x) {
        const int k = idx >> 7, c = idx & 127;
        w1t[swz(c, k)] = (__bf16)W1[idx];
        w2t[swz(c, k)] = (__bf16)W2[idx];
    }
    __syncthreads();

    const int lane = threadIdx.x & 63;
    const int lrow = lane & 15;   // A row within tile / C col within col-tile
    const int lgrp = lane >> 4;   // 0..3
    const int wave   = blockIdx.x * (blockDim.x >> 6) + (threadIdx.x >> 6);
    const int nwaves = gridDim.x * (blockDim.x >> 6);

    float b1v[8], b2v[8];
    #pragma unroll
    for (int ct = 0; ct < 8; ++ct) {
        b1v[ct] = b1[ct * 16 + lrow];
        b2v[ct] = b2[ct * 16 + lrow];
    }

    const int ntiles = N_NODES / 16;   // 12500
    for (int t = wave; t < ntiles; t += nwaves) {
        const int node = t * 16 + lrow;
        f32x4 acc1[8], acc2[8];
        #pragma unroll
        for (int ct = 0; ct < 8; ++ct) {
            acc1[ct] = (f32x4)(0.0f);
            acc2[ct] = (f32x4)(0.0f);
        }

        #pragma unroll
        for (int ks = 0; ks < 4; ++ks) {
            const int kk = ks * 32 + lgrp * 8;   // this lane's 8-k slice
            const f32x4* ep = (const f32x4*)(ego     + (size_t)node * DIM + kk);
            const f32x4* sp = (const f32x4*)(side_in + (size_t)node * DIM + kk);
            const f32x4 e0 = ep[0], e1 = ep[1];
            const f32x4 s0 = sp[0], s1 = sp[1];
            bf16x8 ax, ay;
            #pragma unroll
            for (int j = 0; j < 4; ++j) {
                ax[j]     = (__bf16)(e0[j] + s0[j]);
                ax[j + 4] = (__bf16)(e1[j] + s1[j]);
                ay[j]     = (__bf16)(e0[j] * s0[j]);
                ay[j + 4] = (__bf16)(e1[j] * s1[j]);
            }
            #pragma unroll
            for (int ct = 0; ct < 8; ++ct) {
                const int c = ct * 16 + lrow;
                const bf16x8 bv1 = *(const bf16x8*)&w1t[swz(c, kk)];
                const bf16x8 bv2 = *(const bf16x8*)&w2t[swz(c, kk)];
                acc1[ct] = __builtin_amdgcn_mfma_f32_16x16x32_bf16(ax, bv1, acc1[ct], 0, 0, 0);
                acc2[ct] = __builtin_amdgcn_mfma_f32_16x16x32_bf16(ay, bv2, acc2[ct], 0, 0, 0);
            }
        }

        // epilogue: C lane mapping col = lane&15, row = (lane>>4)*4 + j
        const int orow_base = t * 16 + lgrp * 4;
        #pragma unroll
        for (int ct = 0; ct < 8; ++ct) {
            #pragma unroll
            for (int j = 0; j < 4; ++j) {
                float u = acc1[ct][j] + b1v[ct];
                float w = acc2[ct][j] + b2v[ct];
                u = (u > 0.0f) ? u : 0.01f * u;
                w = (w > 0.0f) ? w : 0.01f * w;
                out[(size_t)(orow_base + j) * DIM + ct * 16 + lrow] = u + w;
            }
        }
    }
}

extern "C" void kernel_launch(void* const* d_in, const int* in_sizes, int n_in,
                              void* d_out, int out_size, void* d_ws, size_t ws_size,
                              hipStream_t stream) {
    const int*   erow = (const int*)d_in[0];
    const int*   ecol = (const int*)d_in[1];
    const float* eval = (const float*)d_in[2];
    const float* ego  = (const float*)d_in[3];
    const float* W1   = (const float*)d_in[4];
    const float* b1   = (const float*)d_in[5];
    const float* W2   = (const float*)d_in[6];
    const float* b2   = (const float*)d_in[7];
    float* out = (float*)d_out;

    // side accumulates directly in d_out (same shape); must zero it ourselves
    // (harness poisons d_out with 0xAA before every timed launch).
    hipMemsetAsync(out, 0, (size_t)N_NODES * DIM * sizeof(float), stream);

    scatter_kernel<<<4096, 256, 0, stream>>>(erow, ecol, eval, ego, out);
    dense_kernel<<<512, 256, 0, stream>>>(ego, out, W1, b1, W2, b2, out);
}

// Round 2
// 2840.248 us; speedup vs baseline: 3.7218x; 3.7218x over previous
//
#include <hip/hip_runtime.h>
#include <hip/hip_bf16.h>

#define N_NODES 200000
#define N_EDGES 12800000
#define DIM 128

typedef float f32x2 __attribute__((ext_vector_type(2)));
typedef float f32x4 __attribute__((ext_vector_type(4)));
typedef __bf16 bf16x8 __attribute__((ext_vector_type(8)));

// ===========================================================================
// CSR build: histogram -> single-block scan -> counting-sort reorder.
// Then gather-side SpMM (no f32 atomics at all).
// ===========================================================================

__global__ __launch_bounds__(256) void hist_kernel(
    const int* __restrict__ erow, int* __restrict__ cnt)
{
    int i = blockIdx.x * blockDim.x + threadIdx.x;
    const int stride = gridDim.x * blockDim.x;
    for (; i < N_EDGES; i += stride)
        atomicAdd(&cnt[erow[i]], 1);
}

// one block, 1024 threads: exclusive scan of cnt[0..N) -> rowptr, cursor.
// cursor may alias cnt (cnt[idx] is read before cursor[idx] is written).
__global__ __launch_bounds__(1024) void scan_kernel(
    const int* cnt, int* __restrict__ rowptr, int* cursor)
{
    __shared__ int lds[1024];
    const int t = threadIdx.x;
    const int CHUNK = (N_NODES + 1023) / 1024;   // 196
    const int base = t * CHUNK;

    int s = 0;
    for (int i = 0; i < CHUNK; ++i) {
        const int idx = base + i;
        if (idx < N_NODES) s += cnt[idx];
    }
    lds[t] = s;
    __syncthreads();
    for (int off = 1; off < 1024; off <<= 1) {
        const int add = (t >= off) ? lds[t - off] : 0;
        __syncthreads();
        lds[t] += add;
        __syncthreads();
    }
    int run = lds[t] - s;   // exclusive prefix of this thread's chunk
    for (int i = 0; i < CHUNK; ++i) {
        const int idx = base + i;
        if (idx < N_NODES) {
            const int c = cnt[idx];     // read BEFORE cursor write (may alias)
            rowptr[idx] = run;
            cursor[idx] = run;
            run += c;
        }
    }
    if (t == 1023) rowptr[N_NODES] = lds[1023];
}

__global__ __launch_bounds__(256) void reorder_kernel(
    const int* __restrict__ erow, const int* __restrict__ ecol,
    const float* __restrict__ eval, int* cursor, int2* __restrict__ sorted)
{
    int i = blockIdx.x * blockDim.x + threadIdx.x;
    const int stride = gridDim.x * blockDim.x;
    for (; i < N_EDGES; i += stride) {
        const int r = erow[i];
        const int pos = atomicAdd(&cursor[r], 1);
        sorted[pos] = make_int2(ecol[i], __float_as_int(eval[i]));
    }
}

// one wave per node: accumulate side[n,:] in registers, write once.
// 4-deep manual load pipeline keeps 4 independent L3 gathers in flight.
__global__ __launch_bounds__(256) void gather_kernel(
    const int* __restrict__ rowptr, const int2* __restrict__ sorted,
    const float* __restrict__ ego, float* __restrict__ side)
{
    const int lane   = threadIdx.x & 63;
    const int wave   = blockIdx.x * (blockDim.x >> 6) + (threadIdx.x >> 6);
    const int nwaves = gridDim.x * (blockDim.x >> 6);

    for (int n = wave; n < N_NODES; n += nwaves) {
        const int start = rowptr[n], end = rowptr[n + 1];
        float a0 = 0.0f, a1 = 0.0f;
        for (int base = start; base < end; base += 64) {
            const int m = end - base;               // wave-uniform
            const int cnt = (m < 64) ? m : 64;
            int2 ev = make_int2(0, 0);
            if (lane < cnt) ev = sorted[base + lane];
            int j = 0;
            for (; j + 4 <= cnt; j += 4) {
                const int c0 = __builtin_amdgcn_readlane(ev.x, j);
                const int c1 = __builtin_amdgcn_readlane(ev.x, j + 1);
                const int c2 = __builtin_amdgcn_readlane(ev.x, j + 2);
                const int c3 = __builtin_amdgcn_readlane(ev.x, j + 3);
                const f32x2 g0 = ((const f32x2*)(ego + (size_t)c0 * DIM))[lane];
                const f32x2 g1 = ((const f32x2*)(ego + (size_t)c1 * DIM))[lane];
                const f32x2 g2 = ((const f32x2*)(ego + (size_t)c2 * DIM))[lane];
                const f32x2 g3 = ((const f32x2*)(ego + (size_t)c3 * DIM))[lane];
                const float v0 = __int_as_float(__builtin_amdgcn_readlane(ev.y, j));
                const float v1 = __int_as_float(__builtin_amdgcn_readlane(ev.y, j + 1));
                const float v2 = __int_as_float(__builtin_amdgcn_readlane(ev.y, j + 2));
                const float v3 = __int_as_float(__builtin_amdgcn_readlane(ev.y, j + 3));
                a0 = fmaf(v0, g0.x, a0); a1 = fmaf(v0, g0.y, a1);
                a0 = fmaf(v1, g1.x, a0); a1 = fmaf(v1, g1.y, a1);
                a0 = fmaf(v2, g2.x, a0); a1 = fmaf(v2, g2.y, a1);
                a0 = fmaf(v3, g3.x, a0); a1 = fmaf(v3, g3.y, a1);
            }
            for (; j < cnt; ++j) {
                const int cj = __builtin_amdgcn_readlane(ev.x, j);
                const float vj = __int_as_float(__builtin_amdgcn_readlane(ev.y, j));
                const f32x2 gv = ((const f32x2*)(ego + (size_t)cj * DIM))[lane];
                a0 = fmaf(vj, gv.x, a0); a1 = fmaf(vj, gv.y, a1);
            }
        }
        f32x2 r; r.x = a0; r.y = a1;
        ((f32x2*)(side + (size_t)n * DIM))[lane] = r;
    }
}

// ---------------------------------------------------------------------------
// Fallback scatter (atomics) — used only if ws is too small for CSR.
// ---------------------------------------------------------------------------
__global__ __launch_bounds__(256) void scatter_kernel(
    const int* __restrict__ erow, const int* __restrict__ ecol,
    const float* __restrict__ eval, const float* __restrict__ ego,
    float* __restrict__ side)
{
    const int lane   = threadIdx.x & 63;
    const int wave   = blockIdx.x * (blockDim.x >> 6) + (threadIdx.x >> 6);
    const int nwaves = gridDim.x * (blockDim.x >> 6);
    const int ngroups = N_EDGES / 64;

    for (int g = wave; g < ngroups; g += nwaves) {
        const int e = g * 64 + lane;
        const int r = erow[e];
        const int c = ecol[e];
        const float v = eval[e];
        #pragma unroll 4
        for (int j = 0; j < 64; ++j) {
            const int rj = __builtin_amdgcn_readlane(r, j);
            const int cj = __builtin_amdgcn_readlane(c, j);
            const float vj = __int_as_float(__builtin_amdgcn_readlane(__float_as_int(v), j));
            const f32x2 gv = ((const f32x2*)(ego + (size_t)cj * DIM))[lane];
            float* dst = side + (size_t)rj * DIM + lane * 2;
            unsafeAtomicAdd(dst,     vj * gv.x);
            unsafeAtomicAdd(dst + 1, vj * gv.y);
        }
    }
}

// ---------------------------------------------------------------------------
// Phase 2: out = lrelu((ego+side)@W1 + b1) + lrelu((ego*side)@W2 + b2)
// bf16 MFMA 16x16x32, W^T in swizzled LDS.  (unchanged from round 1)
// ---------------------------------------------------------------------------
__device__ __forceinline__ int swz(int c, int k) {
    return c * DIM + ((((k >> 3) ^ (c & 7)) << 3) | (k & 7));
}

__global__ __launch_bounds__(256) void dense_kernel(
    const float* __restrict__ ego, const float* side_in,
    const float* __restrict__ W1, const float* __restrict__ b1,
    const float* __restrict__ W2, const float* __restrict__ b2,
    float* out)
{
    __shared__ __bf16 w1t[DIM * DIM];
    __shared__ __bf16 w2t[DIM * DIM];

    for (int idx = threadIdx.x; idx < DIM * DIM; idx += blockDim.x) {
        const int k = idx >> 7, c = idx & 127;
        w1t[swz(c, k)] = (__bf16)W1[idx];
        w2t[swz(c, k)] = (__bf16)W2[idx];
    }
    __syncthreads();

    const int lane = threadIdx.x & 63;
    const int lrow = lane & 15;
    const int lgrp = lane >> 4;
    const int wave   = blockIdx.x * (blockDim.x >> 6) + (threadIdx.x >> 6);
    const int nwaves = gridDim.x * (blockDim.x >> 6);

    float b1v[8], b2v[8];
    #pragma unroll
    for (int ct = 0; ct < 8; ++ct) {
        b1v[ct] = b1[ct * 16 + lrow];
        b2v[ct] = b2[ct * 16 + lrow];
    }

    const int ntiles = N_NODES / 16;
    for (int t = wave; t < ntiles; t += nwaves) {
        const int node = t * 16 + lrow;
        f32x4 acc1[8], acc2[8];
        #pragma unroll
        for (int ct = 0; ct < 8; ++ct) {
            acc1[ct] = (f32x4)(0.0f);
            acc2[ct] = (f32x4)(0.0f);
        }

        #pragma unroll
        for (int ks = 0; ks < 4; ++ks) {
            const int kk = ks * 32 + lgrp * 8;
            const f32x4* ep = (const f32x4*)(ego     + (size_t)node * DIM + kk);
            const f32x4* sp = (const f32x4*)(side_in + (size_t)node * DIM + kk);
            const f32x4 e0 = ep[0], e1 = ep[1];
            const f32x4 s0 = sp[0], s1 = sp[1];
            bf16x8 ax, ay;
            #pragma unroll
            for (int j = 0; j < 4; ++j) {
                ax[j]     = (__bf16)(e0[j] + s0[j]);
                ax[j + 4] = (__bf16)(e1[j] + s1[j]);
                ay[j]     = (__bf16)(e0[j] * s0[j]);
                ay[j + 4] = (__bf16)(e1[j] * s1[j]);
            }
            #pragma unroll
            for (int ct = 0; ct < 8; ++ct) {
                const int c = ct * 16 + lrow;
                const bf16x8 bv1 = *(const bf16x8*)&w1t[swz(c, kk)];
                const bf16x8 bv2 = *(const bf16x8*)&w2t[swz(c, kk)];
                acc1[ct] = __builtin_amdgcn_mfma_f32_16x16x32_bf16(ax, bv1, acc1[ct], 0, 0, 0);
                acc2[ct] = __builtin_amdgcn_mfma_f32_16x16x32_bf16(ay, bv2, acc2[ct], 0, 0, 0);
            }
        }

        const int orow_base = t * 16 + lgrp * 4;
        #pragma unroll
        for (int ct = 0; ct < 8; ++ct) {
            #pragma unroll
            for (int j = 0; j < 4; ++j) {
                float u = acc1[ct][j] + b1v[ct];
                float w = acc2[ct][j] + b2v[ct];
                u = (u > 0.0f) ? u : 0.01f * u;
                w = (w > 0.0f) ? w : 0.01f * w;
                out[(size_t)(orow_base + j) * DIM + ct * 16 + lrow] = u + w;
            }
        }
    }
}

extern "C" void kernel_launch(void* const* d_in, const int* in_sizes, int n_in,
                              void* d_out, int out_size, void* d_ws, size_t ws_size,
                              hipStream_t stream) {
    const int*   erow = (const int*)d_in[0];
    const int*   ecol = (const int*)d_in[1];
    const float* eval = (const float*)d_in[2];
    const float* ego  = (const float*)d_in[3];
    const float* W1   = (const float*)d_in[4];
    const float* b1   = (const float*)d_in[5];
    const float* W2   = (const float*)d_in[6];
    const float* b2   = (const float*)d_in[7];
    float* out = (float*)d_out;

    // workspace layout
    const size_t sz_rowptr = (size_t)(N_NODES + 1) * sizeof(int);
    const size_t off_cnt   = (sz_rowptr + 255) & ~(size_t)255;
    const size_t sz_cnt    = (size_t)N_NODES * sizeof(int);
    const size_t off_sorted = (off_cnt + sz_cnt + 255) & ~(size_t)255;
    const size_t need = off_sorted + (size_t)N_EDGES * sizeof(int2);

    if (ws_size >= need) {
        int*  rowptr = (int*)d_ws;
        int*  cnt    = (int*)((char*)d_ws + off_cnt);   // doubles as cursor
        int2* sorted = (int2*)((char*)d_ws + off_sorted);

        hipMemsetAsync(cnt, 0, sz_cnt, stream);
        hist_kernel   <<<4096, 256, 0, stream>>>(erow, cnt);
        scan_kernel   <<<1, 1024, 0, stream>>>(cnt, rowptr, cnt);
        reorder_kernel<<<4096, 256, 0, stream>>>(erow, ecol, eval, cnt, sorted);
        gather_kernel <<<2048, 256, 0, stream>>>(rowptr, sorted, ego, out);
    } else {
        hipMemsetAsync(out, 0, (size_t)N_NODES * DIM * sizeof(float), stream);
        scatter_kernel<<<4096, 256, 0, stream>>>(erow, ecol, eval, ego, out);
    }
    dense_kernel<<<512, 256, 0, stream>>>(ego, out, W1, b1, W2, b2, out);
}

// Round 3
// 1941.704 us; speedup vs baseline: 5.4440x; 1.4628x over previous
//
#include <hip/hip_runtime.h>
#include <hip/hip_bf16.h>

#define N_NODES 200000
#define N_EDGES 12800000
#define DIM 128
#define NBLK 782   // ceil(N_NODES / 256)

typedef float f32x2 __attribute__((ext_vector_type(2)));
typedef float f32x4 __attribute__((ext_vector_type(4)));
typedef __bf16 bf16x8 __attribute__((ext_vector_type(8)));

// ===========================================================================
// CSR build: histogram -> 3-kernel scan -> counting-sort reorder (4B packed
// entries: col<<14 | val_q14).  Gather-side SpMM reads bf16 ego (halved
// beyond-L2 traffic).  No f32 atomics anywhere.
// ===========================================================================

// ego f32 -> packed bf16 pairs (RNE), one dword = dims {2i, 2i+1}
__global__ __launch_bounds__(256) void cast_kernel(
    const float* __restrict__ ego, unsigned int* __restrict__ egob)
{
    const int total = N_NODES * DIM / 2;
    int i = blockIdx.x * blockDim.x + threadIdx.x;
    const int stride = gridDim.x * blockDim.x;
    for (; i < total; i += stride) {
        const f32x2 v = ((const f32x2*)ego)[i];
        unsigned ux = __float_as_uint(v.x), uy = __float_as_uint(v.y);
        ux = (ux + 0x7fffu + ((ux >> 16) & 1u)) >> 16;   // RNE to bf16
        uy = (uy + 0x7fffu + ((uy >> 16) & 1u)) >> 16;
        egob[i] = ux | (uy << 16);
    }
}

__global__ __launch_bounds__(256) void hist_kernel(
    const int* __restrict__ erow, int* __restrict__ cnt)
{
    int i = blockIdx.x * blockDim.x + threadIdx.x;
    const int stride = gridDim.x * blockDim.x;
    for (; i < N_EDGES; i += stride)
        atomicAdd(&cnt[erow[i]], 1);
}

// --- 3-kernel exclusive scan of cnt[0..N) -> rowptr, cursor ---
__global__ __launch_bounds__(256) void scan_reduce(
    const int* __restrict__ cnt, int* __restrict__ bsum)
{
    __shared__ int lds[256];
    const int idx = blockIdx.x * 256 + threadIdx.x;
    lds[threadIdx.x] = (idx < N_NODES) ? cnt[idx] : 0;
    __syncthreads();
    for (int off = 128; off > 0; off >>= 1) {
        if (threadIdx.x < off) lds[threadIdx.x] += lds[threadIdx.x + off];
        __syncthreads();
    }
    if (threadIdx.x == 0) bsum[blockIdx.x] = lds[0];
}

__global__ __launch_bounds__(1024) void scan_top(
    const int* __restrict__ bsum, int* __restrict__ bpre)
{
    __shared__ int lds[1024];
    const int t = threadIdx.x;
    const int v = (t < NBLK) ? bsum[t] : 0;
    lds[t] = v;
    __syncthreads();
    for (int off = 1; off < 1024; off <<= 1) {
        const int add = (t >= off) ? lds[t - off] : 0;
        __syncthreads();
        lds[t] += add;
        __syncthreads();
    }
    if (t < NBLK) bpre[t] = lds[t] - v;   // exclusive prefix of block sums
}

__global__ __launch_bounds__(256) void scan_local(
    const int* cnt, const int* __restrict__ bpre,
    int* __restrict__ rowptr, int* cursor)   // cursor may alias cnt
{
    __shared__ int lds[256];
    const int t = threadIdx.x;
    const int idx = blockIdx.x * 256 + t;
    const int v = (idx < N_NODES) ? cnt[idx] : 0;   // read before alias write
    lds[t] = v;
    __syncthreads();
    for (int off = 1; off < 256; off <<= 1) {
        const int add = (t >= off) ? lds[t - off] : 0;
        __syncthreads();
        lds[t] += add;
        __syncthreads();
    }
    const int excl = lds[t] - v + bpre[blockIdx.x];
    if (idx < N_NODES) { rowptr[idx] = excl; cursor[idx] = excl; }
    if (idx == N_NODES - 1) rowptr[N_NODES] = excl + v;
}

// counting-sort: packed entry = (col << 14) | round(val * 16383)
__global__ __launch_bounds__(256) void reorder_kernel(
    const int* __restrict__ erow, const int* __restrict__ ecol,
    const float* __restrict__ eval, int* cursor, unsigned int* __restrict__ sorted)
{
    int i = blockIdx.x * blockDim.x + threadIdx.x;
    const int stride = gridDim.x * blockDim.x;
    for (; i < N_EDGES; i += stride) {
        const int r = erow[i];
        const int pos = atomicAdd(&cursor[r], 1);
        const unsigned q = (unsigned)__float2int_rn(eval[i] * 16383.0f);
        sorted[pos] = ((unsigned)ecol[i] << 14) | q;
    }
}

// one wave per node: accumulate side[n,:] in registers (f32), write once.
// 8-deep unroll keeps 8 independent bf16-pair gathers in flight.
__global__ __launch_bounds__(256) void gather_kernel(
    const int* __restrict__ rowptr, const unsigned int* __restrict__ sorted,
    const unsigned int* __restrict__ egob, float* __restrict__ side)
{
    const int lane   = threadIdx.x & 63;
    const int wave   = blockIdx.x * (blockDim.x >> 6) + (threadIdx.x >> 6);
    const int nwaves = gridDim.x * (blockDim.x >> 6);
    const float qs = 1.0f / 16383.0f;

    for (int n = wave; n < N_NODES; n += nwaves) {
        const int start = rowptr[n], end = rowptr[n + 1];
        float a0 = 0.0f, a1 = 0.0f;
        for (int base = start; base < end; base += 64) {
            const int m = end - base;               // wave-uniform
            const int cnt = (m < 64) ? m : 64;
            unsigned w = 0;
            if (lane < cnt) w = sorted[base + lane];
            int j = 0;
            for (; j + 8 <= cnt; j += 8) {
                unsigned ww[8], dd[8];
                #pragma unroll
                for (int u = 0; u < 8; ++u)
                    ww[u] = __builtin_amdgcn_readlane(w, j + u);
                #pragma unroll
                for (int u = 0; u < 8; ++u)
                    dd[u] = egob[(size_t)(ww[u] >> 14) * (DIM / 2) + lane];
                #pragma unroll
                for (int u = 0; u < 8; ++u) {
                    const float vv = (float)(ww[u] & 16383u) * qs;
                    a0 = fmaf(vv, __uint_as_float(dd[u] << 16), a0);
                    a1 = fmaf(vv, __uint_as_float(dd[u] & 0xffff0000u), a1);
                }
            }
            for (; j < cnt; ++j) {
                const unsigned wj = __builtin_amdgcn_readlane(w, j);
                const unsigned dj = egob[(size_t)(wj >> 14) * (DIM / 2) + lane];
                const float vj = (float)(wj & 16383u) * qs;
                a0 = fmaf(vj, __uint_as_float(dj << 16), a0);
                a1 = fmaf(vj, __uint_as_float(dj & 0xffff0000u), a1);
            }
        }
        f32x2 r; r.x = a0; r.y = a1;
        ((f32x2*)(side + (size_t)n * DIM))[lane] = r;   // dims {2*lane, 2*lane+1}
    }
}

// ---------------------------------------------------------------------------
// Fallback scatter (atomics) — used only if ws is too small for CSR.
// ---------------------------------------------------------------------------
__global__ __launch_bounds__(256) void scatter_kernel(
    const int* __restrict__ erow, const int* __restrict__ ecol,
    const float* __restrict__ eval, const float* __restrict__ ego,
    float* __restrict__ side)
{
    const int lane   = threadIdx.x & 63;
    const int wave   = blockIdx.x * (blockDim.x >> 6) + (threadIdx.x >> 6);
    const int nwaves = gridDim.x * (blockDim.x >> 6);
    const int ngroups = N_EDGES / 64;

    for (int g = wave; g < ngroups; g += nwaves) {
        const int e = g * 64 + lane;
        const int r = erow[e];
        const int c = ecol[e];
        const float v = eval[e];
        #pragma unroll 4
        for (int j = 0; j < 64; ++j) {
            const int rj = __builtin_amdgcn_readlane(r, j);
            const int cj = __builtin_amdgcn_readlane(c, j);
            const float vj = __int_as_float(__builtin_amdgcn_readlane(__float_as_int(v), j));
            const f32x2 gv = ((const f32x2*)(ego + (size_t)cj * DIM))[lane];
            float* dst = side + (size_t)rj * DIM + lane * 2;
            unsafeAtomicAdd(dst,     vj * gv.x);
            unsafeAtomicAdd(dst + 1, vj * gv.y);
        }
    }
}

// ---------------------------------------------------------------------------
// Phase 2: out = lrelu((ego+side)@W1 + b1) + lrelu((ego*side)@W2 + b2)
// bf16 MFMA 16x16x32, W^T in swizzled LDS.
// ---------------------------------------------------------------------------
__device__ __forceinline__ int swz(int c, int k) {
    return c * DIM + ((((k >> 3) ^ (c & 7)) << 3) | (k & 7));
}

__global__ __launch_bounds__(256) void dense_kernel(
    const float* __restrict__ ego, const float* side_in,
    const float* __restrict__ W1, const float* __restrict__ b1,
    const float* __restrict__ W2, const float* __restrict__ b2,
    float* out)
{
    __shared__ __bf16 w1t[DIM * DIM];
    __shared__ __bf16 w2t[DIM * DIM];

    for (int idx = threadIdx.x; idx < DIM * DIM; idx += blockDim.x) {
        const int k = idx >> 7, c = idx & 127;
        w1t[swz(c, k)] = (__bf16)W1[idx];
        w2t[swz(c, k)] = (__bf16)W2[idx];
    }
    __syncthreads();

    const int lane = threadIdx.x & 63;
    const int lrow = lane & 15;
    const int lgrp = lane >> 4;
    const int wave   = blockIdx.x * (blockDim.x >> 6) + (threadIdx.x >> 6);
    const int nwaves = gridDim.x * (blockDim.x >> 6);

    float b1v[8], b2v[8];
    #pragma unroll
    for (int ct = 0; ct < 8; ++ct) {
        b1v[ct] = b1[ct * 16 + lrow];
        b2v[ct] = b2[ct * 16 + lrow];
    }

    const int ntiles = N_NODES / 16;
    for (int t = wave; t < ntiles; t += nwaves) {
        const int node = t * 16 + lrow;
        f32x4 acc1[8], acc2[8];
        #pragma unroll
        for (int ct = 0; ct < 8; ++ct) {
            acc1[ct] = (f32x4)(0.0f);
            acc2[ct] = (f32x4)(0.0f);
        }

        #pragma unroll
        for (int ks = 0; ks < 4; ++ks) {
            const int kk = ks * 32 + lgrp * 8;
            const f32x4* ep = (const f32x4*)(ego     + (size_t)node * DIM + kk);
            const f32x4* sp = (const f32x4*)(side_in + (size_t)node * DIM + kk);
            const f32x4 e0 = ep[0], e1 = ep[1];
            const f32x4 s0 = sp[0], s1 = sp[1];
            bf16x8 ax, ay;
            #pragma unroll
            for (int j = 0; j < 4; ++j) {
                ax[j]     = (__bf16)(e0[j] + s0[j]);
                ax[j + 4] = (__bf16)(e1[j] + s1[j]);
                ay[j]     = (__bf16)(e0[j] * s0[j]);
                ay[j + 4] = (__bf16)(e1[j] * s1[j]);
            }
            #pragma unroll
            for (int ct = 0; ct < 8; ++ct) {
                const int c = ct * 16 + lrow;
                const bf16x8 bv1 = *(const bf16x8*)&w1t[swz(c, kk)];
                const bf16x8 bv2 = *(const bf16x8*)&w2t[swz(c, kk)];
                acc1[ct] = __builtin_amdgcn_mfma_f32_16x16x32_bf16(ax, bv1, acc1[ct], 0, 0, 0);
                acc2[ct] = __builtin_amdgcn_mfma_f32_16x16x32_bf16(ay, bv2, acc2[ct], 0, 0, 0);
            }
        }

        const int orow_base = t * 16 + lgrp * 4;
        #pragma unroll
        for (int ct = 0; ct < 8; ++ct) {
            #pragma unroll
            for (int j = 0; j < 4; ++j) {
                float u = acc1[ct][j] + b1v[ct];
                float w = acc2[ct][j] + b2v[ct];
                u = (u > 0.0f) ? u : 0.01f * u;
                w = (w > 0.0f) ? w : 0.01f * w;
                out[(size_t)(orow_base + j) * DIM + ct * 16 + lrow] = u + w;
            }
        }
    }
}

extern "C" void kernel_launch(void* const* d_in, const int* in_sizes, int n_in,
                              void* d_out, int out_size, void* d_ws, size_t ws_size,
                              hipStream_t stream) {
    const int*   erow = (const int*)d_in[0];
    const int*   ecol = (const int*)d_in[1];
    const float* eval = (const float*)d_in[2];
    const float* ego  = (const float*)d_in[3];
    const float* W1   = (const float*)d_in[4];
    const float* b1   = (const float*)d_in[5];
    const float* W2   = (const float*)d_in[6];
    const float* b2   = (const float*)d_in[7];
    float* out = (float*)d_out;

    // workspace layout (256B-aligned slabs)
    size_t off = 0;
    auto alloc = [&](size_t bytes) { size_t o = off; off = (off + bytes + 255) & ~(size_t)255; return o; };
    const size_t o_rowptr = alloc((size_t)(N_NODES + 1) * sizeof(int));
    const size_t o_cnt    = alloc((size_t)N_NODES * sizeof(int));
    const size_t o_bsum   = alloc((size_t)NBLK * sizeof(int));
    const size_t o_bpre   = alloc((size_t)NBLK * sizeof(int));
    const size_t o_sorted = alloc((size_t)N_EDGES * sizeof(unsigned int));
    const size_t o_egob   = alloc((size_t)N_NODES * (DIM / 2) * sizeof(unsigned int));
    const size_t need = off;

    if (ws_size >= need) {
        int*      rowptr = (int*)((char*)d_ws + o_rowptr);
        int*      cnt    = (int*)((char*)d_ws + o_cnt);    // doubles as cursor
        int*      bsum   = (int*)((char*)d_ws + o_bsum);
        int*      bpre   = (int*)((char*)d_ws + o_bpre);
        unsigned* sorted = (unsigned*)((char*)d_ws + o_sorted);
        unsigned* egob   = (unsigned*)((char*)d_ws + o_egob);

        hipMemsetAsync(cnt, 0, (size_t)N_NODES * sizeof(int), stream);
        cast_kernel   <<<4096, 256, 0, stream>>>(ego, egob);
        hist_kernel   <<<4096, 256, 0, stream>>>(erow, cnt);
        scan_reduce   <<<NBLK, 256, 0, stream>>>(cnt, bsum);
        scan_top      <<<1, 1024, 0, stream>>>(bsum, bpre);
        scan_local    <<<NBLK, 256, 0, stream>>>(cnt, bpre, rowptr, cnt);
        reorder_kernel<<<4096, 256, 0, stream>>>(erow, ecol, eval, cnt, sorted);
        gather_kernel <<<4096, 256, 0, stream>>>(rowptr, sorted, egob, out);
    } else {
        hipMemsetAsync(out, 0, (size_t)N_NODES * DIM * sizeof(float), stream);
        scatter_kernel<<<4096, 256, 0, stream>>>(erow, ecol, eval, ego, out);
    }
    dense_kernel<<<512, 256, 0, stream>>>(ego, out, W1, b1, W2, b2, out);
}